// Round 6
// baseline (163.481 us; speedup 1.0000x reference)
//
#include <hip/hip_runtime.h>
#include <hip/hip_fp16.h>

#define N_NODES  100000
#define N_RADIAL 16
#define N_CONICAL 16

#define NPB    64                                    // nodes per bucket (R16: fine buckets)
#define NBKT   1563                                  // ceil(100000/64)
#define NBLK_A 256                                   // binfuse scatter blocks
#define BTHR   512                                   // binfuse block threads
#define CHUNK  12500                                 // edges per scatter block (exact)
#define BINSTRIDE 12544                              // padded block region
#define CAP    2688                                  // bucket cap (mean 2048 + 14σ)
#define FTHR   256                                   // fused aggmlp threads

// ---------------------------------------------------------------------------
// A. R15-verified in-LDS counting sort (write amp 1.0), R16: bucket = row>>6
//    (NPB=64 — free under the dense format) and 25-bucket/lane wave-0 scan.
//    Blocks 0..255: count -> scan -> LDS scatter -> coalesced dense flush.
//    Block 256: W1/W2 transposes. Blocks 257..: xcon f16 pack.
// ---------------------------------------------------------------------------
__global__ __launch_bounds__(BTHR) void binfuse_kernel(
    const int* __restrict__ idx, const float* __restrict__ x,
    __half2* __restrict__ xcon2,
    const float* __restrict__ W1, const float* __restrict__ W2,
    float* __restrict__ W1t, float* __restrict__ W2t,
    unsigned int* __restrict__ binned, int* __restrict__ cnts,
    int* __restrict__ offs, int total, int E) {
    int b = blockIdx.x, tid = threadIdx.x;
    if (b >= NBLK_A) {
        int pb = b - NBLK_A;
        if (pb == 0) {                       // weight transposes (4096 each)
            for (int i = tid; i < 4096; i += BTHR) {
                int c = i >> 7, k = i & 127;
                W1t[k * 32 + c] = W1[i];     // W1[c][k] -> W1t[k][c]
                int kk = i >> 5, o = i & 31;
                W2t[o * 128 + kk] = W2[i];   // W2[k][o] -> W2t[o][k]
            }
        } else {                             // xcon pack: one float4 -> uint2/thread
            int t = (pb - 1) * BTHR + tid;
            if (t < N_NODES * 4) {
                int n = t >> 2, p = t & 3;
                float4 v = *((const float4*)(x + (size_t)n * 32 + 16) + p);
                __half2 h0 = __floats2half2_rn(v.x, v.y);
                __half2 h1 = __floats2half2_rn(v.z, v.w);
                uint2 st;
                st.x = *(unsigned int*)&h0; st.y = *(unsigned int*)&h1;
                *(uint2*)(xcon2 + 2 * t) = st;
            }
        }
        return;
    }

    __shared__ int cnt[NBKT];
    __shared__ int loff[NBKT];
    __shared__ unsigned int stage[CHUNK];    // 50 KB dense staging
    for (int i = tid; i < NBKT; i += BTHR) cnt[i] = 0;
    __syncthreads();

    int lo = b * CHUNK;                      // E/CHUNK = 128 -> block-uniform split
    int cofs = (lo >= E) ? -E : E;
    const int4* rp = (const int4*)(idx + lo);
    const int4* cp = (const int4*)(idx + lo + cofs);
    int nq = CHUNK >> 2;                     // 3125 quads

    // pass 1: per-bucket counts
    #pragma unroll 1
    for (int q = tid; q < nq; q += BTHR) {
        int4 r = rp[q];
        atomicAdd(&cnt[r.x >> 6], 1);
        atomicAdd(&cnt[r.y >> 6], 1);
        atomicAdd(&cnt[r.z >> 6], 1);
        atomicAdd(&cnt[r.w >> 6], 1);
    }
    __syncthreads();

    // pass 2: exclusive scan over 1563 buckets by wave 0 (25 buckets/lane)
    if (tid < 64) {
        int c[25]; int s = 0;
        #pragma unroll
        for (int u = 0; u < 25; u++) {
            int i = tid * 25 + u;
            c[u] = (i < NBKT) ? cnt[i] : 0;
            s += c[u];
        }
        int t = s;
        #pragma unroll
        for (int off = 1; off < 64; off <<= 1) {
            int u = __shfl_up(t, off, 64);
            if (tid >= off) t += u;
        }
        int ex = t - s;
        #pragma unroll
        for (int u = 0; u < 25; u++) {
            int i = tid * 25 + u;
            if (i < NBKT) { loff[i] = ex; ex += c[u]; }
        }
    }
    __syncthreads();

    // publish exact lengths + starts for aggmlp
    for (int i = tid; i < NBKT; i += BTHR) {
        cnts[i * NBLK_A + b] = cnt[i];
        offs[i * NBLK_A + b] = loff[i];
    }
    __syncthreads();                         // loff reads done before cursor use

    // pass 3: scatter into dense LDS stage (loff as cursors)
    #pragma unroll 1
    for (int q = tid; q < nq; q += BTHR) {
        int4 r = rp[q];
        int4 c = cp[q];
        int p0 = atomicAdd(&loff[r.x >> 6], 1);
        int p1 = atomicAdd(&loff[r.y >> 6], 1);
        int p2 = atomicAdd(&loff[r.z >> 6], 1);
        int p3 = atomicAdd(&loff[r.w >> 6], 1);
        stage[p0] = ((unsigned int)(r.x & 63) << 17) | (unsigned int)c.x;
        stage[p1] = ((unsigned int)(r.y & 63) << 17) | (unsigned int)c.y;
        stage[p2] = ((unsigned int)(r.z & 63) << 17) | (unsigned int)c.z;
        stage[p3] = ((unsigned int)(r.w & 63) << 17) | (unsigned int)c.w;
    }
    __syncthreads();

    // pass 4: coalesced full-line flush (write amp 1.0)
    unsigned int* dst = binned + (size_t)b * BINSTRIDE;
    for (int i = tid; i < CHUNK; i += BTHR) dst[i] = stage[i];
}

// ---------------------------------------------------------------------------
// B. R16: fused aggregate+MLP, one 256-thread block per 64-node bucket.
//    Fixes R13's fusion trap: 16.9KB LDS overlay (sedge -> aex -> H2) and
//    256 threads -> 8 blocks/CU co-resident (R13: 66KB -> 2/CU), grid 1563
//    (R13: 391) — co-resident blocks hide each other's serial phases.
//    Pass bodies are the R12/R15-verified ones; MLP is the verified
//    two-phase structure at 4 waves (32 k / 8 outs per wave).
//    Bijective XCD swizzle (m204) for binned/cnts L2 locality.
// ---------------------------------------------------------------------------
__global__ __launch_bounds__(FTHR, 8) void aggmlp_kernel(
    const __half* __restrict__ xcon, const int* __restrict__ cnts,
    const int* __restrict__ offs, const unsigned int* __restrict__ binned,
    const float* __restrict__ x,
    const float* __restrict__ W1t, const float* __restrict__ b1,
    const float* __restrict__ W2t, const float* __restrict__ b2,
    float* __restrict__ out) {
    __shared__ __align__(16) unsigned char smem[16896];  // sedge|aex|H2 overlay
    __shared__ int scnt[NPB];
    __shared__ int soff[NPB];
    unsigned int* sedge = (unsigned int*)smem;           // [CAP] 10.5 KB
    float*        aex   = (float*)smem;                  // [16][64] 4 KB
    __half2*      H2    = (__half2*)smem;                // [64][64] 16 KB

    // bijective XCD-chunked bucket mapping (nwg=1563: q=195, r=3)
    int orig = blockIdx.x;
    int xcd = orig & 7, i8 = orig >> 3;
    const int q = NBKT >> 3, r = NBKT & 7;
    int b = (xcd < r) ? xcd * (q + 1) + i8
                      : r * (q + 1) + (xcd - r) * q + i8;
    int tid = threadIdx.x;
    if (tid < NPB) scnt[tid] = 0;
    __syncthreads();

    // one lane per src-block sub-run (mean 8 edges)
    int sc = cnts[b * NBLK_A + tid];
    unsigned int base = (unsigned int)tid * BINSTRIDE
                      + (unsigned int)offs[b * NBLK_A + tid];

    // pass 1: per-node counts
    for (int j = 0; j < sc; j++)
        atomicAdd(&scnt[binned[base + j] >> 17], 1);
    __syncthreads();

    // pass 2: exclusive scan of 64 counts by wave 0 (shuffle scan)
    if (tid < 64) {
        int c = scnt[tid];
        int t = c;
        #pragma unroll
        for (int off = 1; off < 64; off <<= 1) {
            int u = __shfl_up(t, off, 64);
            if (tid >= off) t += u;
        }
        soff[tid] = t - c;
    }
    __syncthreads();

    // pass 3: scatter into node-sorted sedge (L2/L3-hot re-read)
    for (int j = 0; j < sc; j++) {
        unsigned int p = binned[base + j];
        int pos = atomicAdd(&soff[p >> 17], 1);
        sedge[pos] = p & 0x1FFFFu;
    }
    __syncthreads();

    // pass 4: accumulate, 2 lanes/node, 16B gathers from cached xcon
    int nl = tid >> 1, qh = tid & 1;
    float a0 = 0.f, a1 = 0.f, a2 = 0.f, a3 = 0.f;
    float a4 = 0.f, a5 = 0.f, a6 = 0.f, a7 = 0.f;
    int c4 = 0;
    if (tid < 2 * NPB) {
        c4 = scnt[nl];
        int s0 = soff[nl] - c4;                // soff advanced to row end
        #pragma unroll 2
        for (int k = 0; k < c4; k++) {
            int col = (int)sedge[s0 + k];      // broadcast within pair
            uint4 raw = ((const uint4*)(xcon + (size_t)col * 16))[qh];
            float2 f0 = __half22float2(*(const __half2*)&raw.x);
            float2 f1 = __half22float2(*(const __half2*)&raw.y);
            float2 f2 = __half22float2(*(const __half2*)&raw.z);
            float2 f3 = __half22float2(*(const __half2*)&raw.w);
            a0 += f0.x; a1 += f0.y; a2 += f1.x; a3 += f1.y;
            a4 += f2.x; a5 += f2.y; a6 += f3.x; a7 += f3.y;
        }
    }
    __syncthreads();                           // all sedge reads done

    if (tid < 2 * NPB) {                       // agg -> LDS handoff (overlays sedge)
        float inv = 1.0f / (float)max(c4, 1);
        int j0 = qh * 8;
        aex[(j0 + 0) * 64 + nl] = a0 * inv;
        aex[(j0 + 1) * 64 + nl] = a1 * inv;
        aex[(j0 + 2) * 64 + nl] = a2 * inv;
        aex[(j0 + 3) * 64 + nl] = a3 * inv;
        aex[(j0 + 4) * 64 + nl] = a4 * inv;
        aex[(j0 + 5) * 64 + nl] = a5 * inv;
        aex[(j0 + 6) * 64 + nl] = a6 * inv;
        aex[(j0 + 7) * 64 + nl] = a7 * inv;
    }
    __syncthreads();

    // ---------------- in-block MLP (verified two-phase, 4 waves) ----------
    int lane = tid & 63;
    int ws   = __builtin_amdgcn_readfirstlane(tid >> 6);   // wave 0..3
    int n    = b * NPB + lane;
    int ncl  = min(n, N_NODES - 1);

    float comb[32];
    const float4* xr = (const float4*)(x + (size_t)ncl * 32);
    #pragma unroll
    for (int cc = 0; cc < 4; cc++) {
        float4 v = xr[cc];
        comb[cc*4+0] = v.x; comb[cc*4+1] = v.y;
        comb[cc*4+2] = v.z; comb[cc*4+3] = v.w;
    }
    #pragma unroll
    for (int j = 0; j < 16; j++)
        comb[16 + j] = aex[j * 64 + lane];
    __syncthreads();                           // aex dead; H2 region free

    // phase A: wave ws computes h[k] for k in [ws*32, ws*32+32)
    #pragma unroll
    for (int i = 0; i < 32; i += 2) {
        int k0 = ws * 32 + i;
        const float* w1a = W1t + k0 * 32;
        const float* w1b = w1a + 32;
        float ha = b1[k0], hb = b1[k0 + 1];
        #pragma unroll
        for (int cc = 0; cc < 32; cc++) {
            ha = fmaf(comb[cc], w1a[cc], ha);
            hb = fmaf(comb[cc], w1b[cc], hb);
        }
        ha = fmaxf(ha, 0.f); hb = fmaxf(hb, 0.f);
        H2[(k0 >> 1) * 64 + lane] = __floats2half2_rn(ha, hb);
    }
    __syncthreads();

    // phase B: wave ws computes outs o in [ws*8, ws*8+8)
    int o0 = ws * 8;
    const float* w20 = W2t + (o0 + 0) * 128;
    const float* w21 = W2t + (o0 + 1) * 128;
    const float* w22 = W2t + (o0 + 2) * 128;
    const float* w23 = W2t + (o0 + 3) * 128;
    const float* w24 = W2t + (o0 + 4) * 128;
    const float* w25 = W2t + (o0 + 5) * 128;
    const float* w26 = W2t + (o0 + 6) * 128;
    const float* w27 = W2t + (o0 + 7) * 128;
    float acc0 = b2[o0+0], acc1 = b2[o0+1], acc2 = b2[o0+2], acc3 = b2[o0+3];
    float acc4 = b2[o0+4], acc5 = b2[o0+5], acc6 = b2[o0+6], acc7 = b2[o0+7];
    #pragma unroll 4
    for (int kp = 0; kp < 64; kp++) {
        float2 h = __half22float2(H2[kp * 64 + lane]);
        int k0 = 2 * kp;
        acc0 = fmaf(h.x, w20[k0], acc0); acc0 = fmaf(h.y, w20[k0+1], acc0);
        acc1 = fmaf(h.x, w21[k0], acc1); acc1 = fmaf(h.y, w21[k0+1], acc1);
        acc2 = fmaf(h.x, w22[k0], acc2); acc2 = fmaf(h.y, w22[k0+1], acc2);
        acc3 = fmaf(h.x, w23[k0], acc3); acc3 = fmaf(h.y, w23[k0+1], acc3);
        acc4 = fmaf(h.x, w24[k0], acc4); acc4 = fmaf(h.y, w24[k0+1], acc4);
        acc5 = fmaf(h.x, w25[k0], acc5); acc5 = fmaf(h.y, w25[k0+1], acc5);
        acc6 = fmaf(h.x, w26[k0], acc6); acc6 = fmaf(h.y, w26[k0+1], acc6);
        acc7 = fmaf(h.x, w27[k0], acc7); acc7 = fmaf(h.y, w27[k0+1], acc7);
    }
    if (n < N_NODES) {
        float4 s0v; s0v.x = acc0; s0v.y = acc1; s0v.z = acc2; s0v.w = acc3;
        float4 s1v; s1v.x = acc4; s1v.y = acc5; s1v.z = acc6; s1v.w = acc7;
        float4* op = (float4*)(out + (size_t)n * 32 + o0);
        op[0] = s0v; op[1] = s1v;
    }
}

extern "C" void kernel_launch(void* const* d_in, const int* in_sizes, int n_in,
                              void* d_out, int out_size, void* d_ws, size_t ws_size,
                              hipStream_t stream) {
    const float* x   = (const float*)d_in[0];
    const int*   idx = (const int*)d_in[1];
    const float* W1  = (const float*)d_in[2];
    const float* b1  = (const float*)d_in[3];
    const float* W2  = (const float*)d_in[4];
    const float* b2  = (const float*)d_in[5];
    float* out = (float*)d_out;

    const int E = in_sizes[1] / 2;     // 1,600,000
    const int total = 2 * E;           // 3,200,000

    // ws layout (~19.3 MB):
    //   xcon f16 3.2MB | W1t 16KB | W2t 16KB |
    //   cnts 1563*256*4 = 1.6MB | offs 1.6MB | binned 256*12544*4 = 12.85MB
    char* base = (char*)d_ws;
    __half*       xcon   = (__half*)base;
    float*        W1t    = (float*)(base + 3203072);
    float*        W2t    = (float*)(base + 3219456);
    int*          cnts   = (int*)(base + 3235840);
    int*          offs   = (int*)(base + 4836352);
    unsigned int* binned = (unsigned int*)(base + 6436864);

    int pack_blocks = (N_NODES * 4 + BTHR - 1) / BTHR;   // 782
    binfuse_kernel<<<NBLK_A + 1 + pack_blocks, BTHR, 0, stream>>>(
        idx, x, (__half2*)xcon, W1, W2, W1t, W2t,
        binned, cnts, offs, total, E);
    aggmlp_kernel<<<NBKT, FTHR, 0, stream>>>(
        xcon, cnts, offs, binned, x, W1t, b1, W2t, b2, out);
}

// Round 7
// 149.246 us; speedup vs baseline: 1.0954x; 1.0954x over previous
//
#include <hip/hip_runtime.h>
#include <hip/hip_fp16.h>

#define N_NODES  100000
#define N_RADIAL 16
#define N_CONICAL 16

#define NPB    256                                   // nodes per bucket
#define NBKT   ((N_NODES + NPB - 1) / NPB)           // 391 buckets
#define NBLK_A 500                                   // binfuse scatter blocks (R17: 2/CU)
#define BTHR   512                                   // binfuse block threads
#define CHUNK  6400                                  // edges per scatter block (500*6400=3.2M)
#define BINSTRIDE 6400                               // dense block region (25.6KB, line-aligned)
#define CAP    10240                                 // compacted bucket cap (mean 8192 + 22σ)

// ---------------------------------------------------------------------------
// A. R15-verified in-LDS counting sort (write amp 1.0). R17: 500 scatter
//    blocks x CHUNK 6400 -> 2 blocks/CU co-resident (the occupancy lever
//    R11/R14 tried is now safe: the DENSE format has no per-cell padding,
//    so sub-run count no longer amplifies WRITE/FETCH — predicted flat at
//    ~15.7/12.8MB; only Occ and dur should move).
//    Blocks 0..499: count -> wave-0 scan (391 buckets) -> LDS scatter ->
//    coalesced dense flush. Block 500: W1/W2 transposes. 501..: xcon pack.
// ---------------------------------------------------------------------------
__global__ __launch_bounds__(BTHR) void binfuse_kernel(
    const int* __restrict__ idx, const float* __restrict__ x,
    __half2* __restrict__ xcon2,
    const float* __restrict__ W1, const float* __restrict__ W2,
    float* __restrict__ W1t, float* __restrict__ W2t,
    unsigned int* __restrict__ binned, int* __restrict__ cnts,
    int* __restrict__ offs, int total, int E) {
    int b = blockIdx.x, tid = threadIdx.x;
    if (b >= NBLK_A) {
        int pb = b - NBLK_A;
        if (pb == 0) {                       // weight transposes (4096 each)
            for (int i = tid; i < 4096; i += BTHR) {
                int c = i >> 7, k = i & 127;
                W1t[k * 32 + c] = W1[i];     // W1[c][k] -> W1t[k][c]
                int kk = i >> 5, o = i & 31;
                W2t[o * 128 + kk] = W2[i];   // W2[k][o] -> W2t[o][k]
            }
        } else {                             // xcon pack: one float4 -> uint2/thread
            int t = (pb - 1) * BTHR + tid;
            if (t < N_NODES * 4) {
                int n = t >> 2, p = t & 3;
                float4 v = *((const float4*)(x + (size_t)n * 32 + 16) + p);
                __half2 h0 = __floats2half2_rn(v.x, v.y);
                __half2 h1 = __floats2half2_rn(v.z, v.w);
                uint2 st;
                st.x = *(unsigned int*)&h0; st.y = *(unsigned int*)&h1;
                *(uint2*)(xcon2 + 2 * t) = st;
            }
        }
        return;
    }

    __shared__ int cnt[NBKT];
    __shared__ int loff[NBKT];
    __shared__ unsigned int stage[CHUNK];    // 25.6 KB dense staging
    for (int i = tid; i < NBKT; i += BTHR) cnt[i] = 0;
    __syncthreads();

    int lo = b * CHUNK;                      // E/CHUNK = 250 -> block-uniform split
    int cofs = (lo >= E) ? -E : E;
    const int4* rp = (const int4*)(idx + lo);
    const int4* cp = (const int4*)(idx + lo + cofs);
    int nq = CHUNK >> 2;                     // 1600 quads

    // pass 1: per-bucket counts
    #pragma unroll 1
    for (int q = tid; q < nq; q += BTHR) {
        int4 r = rp[q];
        atomicAdd(&cnt[r.x >> 8], 1);
        atomicAdd(&cnt[r.y >> 8], 1);
        atomicAdd(&cnt[r.z >> 8], 1);
        atomicAdd(&cnt[r.w >> 8], 1);
    }
    __syncthreads();

    // pass 2: exclusive scan over 391 buckets by wave 0 (7 buckets/lane)
    if (tid < 64) {
        int c[7]; int s = 0;
        #pragma unroll
        for (int u = 0; u < 7; u++) {
            int i = tid * 7 + u;
            c[u] = (i < NBKT) ? cnt[i] : 0;
            s += c[u];
        }
        int t = s;
        #pragma unroll
        for (int off = 1; off < 64; off <<= 1) {
            int u = __shfl_up(t, off, 64);
            if (tid >= off) t += u;
        }
        int ex = t - s;
        #pragma unroll
        for (int u = 0; u < 7; u++) {
            int i = tid * 7 + u;
            if (i < NBKT) { loff[i] = ex; ex += c[u]; }
        }
    }
    __syncthreads();

    // publish exact lengths + starts for agg
    for (int i = tid; i < NBKT; i += BTHR) {
        cnts[i * NBLK_A + b] = cnt[i];
        offs[i * NBLK_A + b] = loff[i];
    }
    __syncthreads();                         // loff reads done before cursor use

    // pass 3: scatter into dense LDS stage (loff as cursors; idx re-read L2-hot)
    #pragma unroll 1
    for (int q = tid; q < nq; q += BTHR) {
        int4 r = rp[q];
        int4 c = cp[q];
        int p0 = atomicAdd(&loff[r.x >> 8], 1);
        int p1 = atomicAdd(&loff[r.y >> 8], 1);
        int p2 = atomicAdd(&loff[r.z >> 8], 1);
        int p3 = atomicAdd(&loff[r.w >> 8], 1);
        stage[p0] = ((unsigned int)(r.x & 255) << 17) | (unsigned int)c.x;
        stage[p1] = ((unsigned int)(r.y & 255) << 17) | (unsigned int)c.y;
        stage[p2] = ((unsigned int)(r.z & 255) << 17) | (unsigned int)c.z;
        stage[p3] = ((unsigned int)(r.w & 255) << 17) | (unsigned int)c.w;
    }
    __syncthreads();

    // pass 4: coalesced full-line flush (write amp 1.0)
    unsigned int* dst = binned + (size_t)b * BINSTRIDE;
    for (int i = tid; i < CHUNK; i += BTHR) dst[i] = stage[i];
}

// ---------------------------------------------------------------------------
// B. Bucket accumulate (R12/R15-verified pass bodies). R17: sub-runs now
//    500 x mean 16.4 (2 lanes each); pass-1 register-caches each lane's
//    edges (ev[12], covers sc<=24+l, Poisson(16.4) tail ~2.4% re-reads
//    L2-hot) so pass 3 is atomic->ds_write with no global load; bijective
//    XCD-chunked bucket swizzle (adjacent buckets share binned lines in
//    the dense format -> same-XCD L2 hits).
// ---------------------------------------------------------------------------
__global__ __launch_bounds__(1024, 2) void agg_kernel(
    const __half* __restrict__ xcon, const int* __restrict__ cnts,
    const int* __restrict__ offs,
    const unsigned int* __restrict__ binned, __half* __restrict__ agg) {
    __shared__ unsigned int sedge[CAP];   // 40 KB
    __shared__ int scnt[NPB];
    __shared__ int soff[NPB];
    // bijective XCD-chunked mapping (NBKT=391: q=48, r=7)
    int orig = blockIdx.x;
    int xcd = orig & 7, i8 = orig >> 3;
    const int qq = NBKT >> 3, rr = NBKT & 7;
    int b = (xcd < rr) ? xcd * (qq + 1) + i8
                       : rr * (qq + 1) + (xcd - rr) * qq + i8;
    int tid = threadIdx.x;
    if (tid < NPB) scnt[tid] = 0;
    __syncthreads();

    int sub = tid >> 1, l = tid & 1;      // 500 sub-runs, 2 lanes each
    int sc = 0; unsigned int base = 0;
    if (sub < NBLK_A) {
        sc   = cnts[b * NBLK_A + sub];
        base = (unsigned int)sub * BINSTRIDE
             + (unsigned int)offs[b * NBLK_A + sub];
    }

    // pass 1: load+cache sub-run edges, per-node counts
    unsigned int ev[12];
    #pragma unroll
    for (int u = 0; u < 12; u++) {
        int j = l + 2 * u;
        ev[u] = 0u;
        if (j < sc) {
            ev[u] = binned[base + j];
            atomicAdd(&scnt[ev[u] >> 17], 1);
        }
    }
    for (int j = l + 24; j < sc; j += 2)
        atomicAdd(&scnt[binned[base + j] >> 17], 1);
    __syncthreads();

    // pass 2: exclusive scan of 256 counts by wave 0 (shuffle scan)
    if (tid < 64) {
        int i0 = tid * 4;
        int c0 = scnt[i0], c1 = scnt[i0 + 1], c2 = scnt[i0 + 2], c3 = scnt[i0 + 3];
        int s = c0 + c1 + c2 + c3;
        int t = s;
        #pragma unroll
        for (int off = 1; off < 64; off <<= 1) {
            int u = __shfl_up(t, off, 64);
            if (tid >= off) t += u;
        }
        int ex = t - s;
        soff[i0]     = ex;
        soff[i0 + 1] = ex + c0;
        soff[i0 + 2] = ex + c0 + c1;
        soff[i0 + 3] = ex + c0 + c1 + c2;
    }
    __syncthreads();

    // pass 3: scatter into node-sorted sedge from the register cache
    #pragma unroll
    for (int u = 0; u < 12; u++) {
        int j = l + 2 * u;
        if (j < sc) {
            unsigned int p = ev[u];
            int pos = atomicAdd(&soff[p >> 17], 1);
            sedge[pos] = p & 0x1FFFFu;
        }
    }
    for (int j = l + 24; j < sc; j += 2) {
        unsigned int p = binned[base + j];
        int pos = atomicAdd(&soff[p >> 17], 1);
        sedge[pos] = p & 0x1FFFFu;
    }
    __syncthreads();

    // pass 4: accumulate, 2 lanes/node, 16B gathers from L2-resident xcon
    if (tid < 2 * NPB) {
        int nl = tid >> 1, q = tid & 1;
        int c  = scnt[nl];
        int s0 = soff[nl] - c;                 // soff advanced to row end
        float a0 = 0.f, a1 = 0.f, a2 = 0.f, a3 = 0.f;
        float a4 = 0.f, a5 = 0.f, a6 = 0.f, a7 = 0.f;
        #pragma unroll 2
        for (int k = 0; k < c; k++) {
            int col = (int)sedge[s0 + k];      // broadcast within pair
            uint4 raw = ((const uint4*)(xcon + (size_t)col * 16))[q];
            float2 f0 = __half22float2(*(const __half2*)&raw.x);
            float2 f1 = __half22float2(*(const __half2*)&raw.y);
            float2 f2 = __half22float2(*(const __half2*)&raw.z);
            float2 f3 = __half22float2(*(const __half2*)&raw.w);
            a0 += f0.x; a1 += f0.y; a2 += f1.x; a3 += f1.y;
            a4 += f2.x; a5 += f2.y; a6 += f3.x; a7 += f3.y;
        }
        int n = b * NPB + nl;
        if (n < N_NODES) {
            float inv = 1.0f / (float)max(c, 1);
            __half2 h0 = __floats2half2_rn(a0 * inv, a1 * inv);
            __half2 h1 = __floats2half2_rn(a2 * inv, a3 * inv);
            __half2 h2 = __floats2half2_rn(a4 * inv, a5 * inv);
            __half2 h3 = __floats2half2_rn(a6 * inv, a7 * inv);
            uint4 st;
            st.x = *(unsigned int*)&h0; st.y = *(unsigned int*)&h1;
            st.z = *(unsigned int*)&h2; st.w = *(unsigned int*)&h3;
            *(uint4*)(agg + (size_t)n * 16 + q * 8) = st;   // 16B/lane
        }
    }
}

// ---------------------------------------------------------------------------
// C. MLP (R9/R10/R12/R15-verified): fused two-phase, 8 waves per 64-node
//    tile. Phase A: wave ws computes h[k=ws*16..+15] (k wave-uniform ->
//    W1t on the scalar pipe), h-pairs f16 in LDS H2[kp][node]. Phase B:
//    wave ws computes outs o=ws*4..+3. 12500 waves.
// ---------------------------------------------------------------------------
__global__ __launch_bounds__(512, 4) void mlp_kernel(
    const float* __restrict__ x, const __half* __restrict__ agg,
    const float* __restrict__ W1t, const float* __restrict__ b1,
    const float* __restrict__ W2t, const float* __restrict__ b2,
    float* __restrict__ out, int N) {
    __shared__ __half2 H2[64 * 64];   // [kp][node], 16 KB
    int tid  = threadIdx.x;
    int lane = tid & 63;
    int ws   = __builtin_amdgcn_readfirstlane(tid >> 6);
    int n    = blockIdx.x * 64 + lane;
    int nc   = min(n, N - 1);

    float comb[32];
    const float4* xr = (const float4*)(x + (size_t)nc * 32);
    #pragma unroll
    for (int c = 0; c < 4; c++) {
        float4 v = xr[c];
        comb[c*4+0] = v.x; comb[c*4+1] = v.y;
        comb[c*4+2] = v.z; comb[c*4+3] = v.w;
    }
    const __half2* ar = (const __half2*)(agg + (size_t)nc * 16);
    #pragma unroll
    for (int c = 0; c < 8; c++) {
        float2 f = __half22float2(ar[c]);
        comb[16 + 2*c]     = f.x;
        comb[16 + 2*c + 1] = f.y;
    }

    #pragma unroll
    for (int i = 0; i < 16; i += 2) {
        int k0 = ws * 16 + i;
        const float* w1a = W1t + k0 * 32;
        const float* w1b = w1a + 32;
        float ha = b1[k0], hb = b1[k0 + 1];
        #pragma unroll
        for (int c = 0; c < 32; c++) {
            ha = fmaf(comb[c], w1a[c], ha);
            hb = fmaf(comb[c], w1b[c], hb);
        }
        ha = fmaxf(ha, 0.f); hb = fmaxf(hb, 0.f);
        H2[(k0 >> 1) * 64 + lane] = __floats2half2_rn(ha, hb);
    }
    __syncthreads();

    int o0 = ws * 4;
    const float* w20 = W2t + (o0 + 0) * 128;
    const float* w21 = W2t + (o0 + 1) * 128;
    const float* w22 = W2t + (o0 + 2) * 128;
    const float* w23 = W2t + (o0 + 3) * 128;
    float acc0 = b2[o0+0], acc1 = b2[o0+1], acc2 = b2[o0+2], acc3 = b2[o0+3];
    #pragma unroll 8
    for (int kp = 0; kp < 64; kp++) {
        float2 h = __half22float2(H2[kp * 64 + lane]);
        int k0 = 2 * kp;
        acc0 = fmaf(h.x, w20[k0], acc0); acc0 = fmaf(h.y, w20[k0+1], acc0);
        acc1 = fmaf(h.x, w21[k0], acc1); acc1 = fmaf(h.y, w21[k0+1], acc1);
        acc2 = fmaf(h.x, w22[k0], acc2); acc2 = fmaf(h.y, w22[k0+1], acc2);
        acc3 = fmaf(h.x, w23[k0], acc3); acc3 = fmaf(h.y, w23[k0+1], acc3);
    }
    if (n < N) {
        float* op = out + (size_t)n * 32 + o0;
        op[0] = acc0; op[1] = acc1; op[2] = acc2; op[3] = acc3;
    }
}

extern "C" void kernel_launch(void* const* d_in, const int* in_sizes, int n_in,
                              void* d_out, int out_size, void* d_ws, size_t ws_size,
                              hipStream_t stream) {
    const float* x   = (const float*)d_in[0];
    const int*   idx = (const int*)d_in[1];
    const float* W1  = (const float*)d_in[2];
    const float* b1  = (const float*)d_in[3];
    const float* W2  = (const float*)d_in[4];
    const float* b2  = (const float*)d_in[5];
    float* out = (float*)d_out;

    const int E = in_sizes[1] / 2;     // 1,600,000
    const int total = 2 * E;           // 3,200,000

    // ws layout (~21 MB):
    //   agg f16 3.2MB | xcon f16 3.2MB | W1t 16KB | W2t 16KB |
    //   cnts 391*500*4 = 782KB | offs 782KB | binned 500*6400*4 = 12.8MB
    char* base = (char*)d_ws;
    __half*       agg    = (__half*)base;
    __half*       xcon   = (__half*)(base + 3203072);
    float*        W1t    = (float*)(base + 6406144);
    float*        W2t    = (float*)(base + 6422528);
    int*          cnts   = (int*)(base + 6438912);
    int*          offs   = (int*)(base + 7241728);
    unsigned int* binned = (unsigned int*)(base + 8044544);

    int pack_blocks = (N_NODES * 4 + BTHR - 1) / BTHR;   // 782
    binfuse_kernel<<<NBLK_A + 1 + pack_blocks, BTHR, 0, stream>>>(
        idx, x, (__half2*)xcon, W1, W2, W1t, W2t,
        binned, cnts, offs, total, E);
    agg_kernel<<<NBKT, 1024, 0, stream>>>(xcon, cnts, offs, binned, agg);
    mlp_kernel<<<(N_NODES + 63) / 64, 512, 0, stream>>>(
        x, agg, W1t, b1, W2t, b2, out, N_NODES);
}

// Round 9
// 139.893 us; speedup vs baseline: 1.1686x; 1.0669x over previous
//
#include <hip/hip_runtime.h>
#include <hip/hip_fp16.h>

#define N_NODES  100000
#define N_RADIAL 16
#define N_CONICAL 16

#define NPB    256                                   // nodes per bucket
#define NBKT   ((N_NODES + NPB - 1) / NPB)           // 391 buckets
#define NBLK_A 500                                   // binfuse scatter blocks (2/CU)
#define BTHR   512                                   // binfuse block threads
#define CHUNK  6400                                  // edges per scatter block (500*6400=3.2M)
#define BINSTRIDE 6400                               // dense block region
#define CAP    10240                                 // compacted bucket cap (mean 8192 + 22σ)

typedef _Float16 h2vec __attribute__((ext_vector_type(2)));
static __device__ __forceinline__ float fdot2(__half2 a, __half2 b, float c) {
    h2vec av, bv;
    __builtin_memcpy(&av, &a, 4);
    __builtin_memcpy(&bv, &b, 4);
    return __builtin_amdgcn_fdot2(av, bv, c, false);   // v_dot2_f32_f16
}

// ---------------------------------------------------------------------------
// A. R15/R17-verified in-LDS counting sort (write amp 1.0), 500 blocks.
//    Blocks 0..499: count -> wave-0 scan -> LDS scatter -> dense flush.
//    Block 500: weight re-layouts (R18: W1tr f32 radial [128][16], W1th f16
//    conical [128][16], W2th f16 [32][128] — fdot2 operand formats).
//    Blocks 501..: xcon f16 pack.
// ---------------------------------------------------------------------------
__global__ __launch_bounds__(BTHR) void binfuse_kernel(
    const int* __restrict__ idx, const float* __restrict__ x,
    __half2* __restrict__ xcon2,
    const float* __restrict__ W1, const float* __restrict__ W2,
    float* __restrict__ W1tr, __half* __restrict__ W1th, __half* __restrict__ W2th,
    unsigned int* __restrict__ binned, int* __restrict__ cnts,
    int* __restrict__ offs, int total, int E) {
    int b = blockIdx.x, tid = threadIdx.x;
    if (b >= NBLK_A) {
        int pb = b - NBLK_A;
        if (pb == 0) {                       // weight re-layouts
            for (int i = tid; i < 2048; i += BTHR) {
                int k = i >> 4, c = i & 15;
                W1tr[k * 16 + c] = W1[c * 128 + k];                       // radial f32
                W1th[k * 16 + c] = __float2half(W1[(16 + c) * 128 + k]); // conical f16
            }
            for (int i = tid; i < 4096; i += BTHR) {
                int kk = i >> 5, o = i & 31;
                W2th[o * 128 + kk] = __float2half(W2[i]);                // W2^T f16
            }
        } else {                             // xcon pack: one float4 -> uint2/thread
            int t = (pb - 1) * BTHR + tid;
            if (t < N_NODES * 4) {
                int n = t >> 2, p = t & 3;
                float4 v = *((const float4*)(x + (size_t)n * 32 + 16) + p);
                __half2 h0 = __floats2half2_rn(v.x, v.y);
                __half2 h1 = __floats2half2_rn(v.z, v.w);
                uint2 st;
                st.x = *(unsigned int*)&h0; st.y = *(unsigned int*)&h1;
                *(uint2*)(xcon2 + 2 * t) = st;
            }
        }
        return;
    }

    __shared__ int cnt[NBKT];
    __shared__ int loff[NBKT];
    __shared__ unsigned int stage[CHUNK];    // 25.6 KB dense staging
    for (int i = tid; i < NBKT; i += BTHR) cnt[i] = 0;
    __syncthreads();

    int lo = b * CHUNK;                      // E/CHUNK = 250 -> block-uniform split
    int cofs = (lo >= E) ? -E : E;
    const int4* rp = (const int4*)(idx + lo);
    const int4* cp = (const int4*)(idx + lo + cofs);
    int nq = CHUNK >> 2;                     // 1600 quads

    // pass 1: per-bucket counts
    #pragma unroll 1
    for (int q = tid; q < nq; q += BTHR) {
        int4 r = rp[q];
        atomicAdd(&cnt[r.x >> 8], 1);
        atomicAdd(&cnt[r.y >> 8], 1);
        atomicAdd(&cnt[r.z >> 8], 1);
        atomicAdd(&cnt[r.w >> 8], 1);
    }
    __syncthreads();

    // pass 2: exclusive scan over 391 buckets by wave 0 (7 buckets/lane)
    if (tid < 64) {
        int c[7]; int s = 0;
        #pragma unroll
        for (int u = 0; u < 7; u++) {
            int i = tid * 7 + u;
            c[u] = (i < NBKT) ? cnt[i] : 0;
            s += c[u];
        }
        int t = s;
        #pragma unroll
        for (int off = 1; off < 64; off <<= 1) {
            int u = __shfl_up(t, off, 64);
            if (tid >= off) t += u;
        }
        int ex = t - s;
        #pragma unroll
        for (int u = 0; u < 7; u++) {
            int i = tid * 7 + u;
            if (i < NBKT) { loff[i] = ex; ex += c[u]; }
        }
    }
    __syncthreads();

    // publish exact lengths + starts for agg
    for (int i = tid; i < NBKT; i += BTHR) {
        cnts[i * NBLK_A + b] = cnt[i];
        offs[i * NBLK_A + b] = loff[i];
    }
    __syncthreads();                         // loff reads done before cursor use

    // pass 3: scatter into dense LDS stage (loff as cursors; idx re-read L2-hot)
    #pragma unroll 1
    for (int q = tid; q < nq; q += BTHR) {
        int4 r = rp[q];
        int4 c = cp[q];
        int p0 = atomicAdd(&loff[r.x >> 8], 1);
        int p1 = atomicAdd(&loff[r.y >> 8], 1);
        int p2 = atomicAdd(&loff[r.z >> 8], 1);
        int p3 = atomicAdd(&loff[r.w >> 8], 1);
        stage[p0] = ((unsigned int)(r.x & 255) << 17) | (unsigned int)c.x;
        stage[p1] = ((unsigned int)(r.y & 255) << 17) | (unsigned int)c.y;
        stage[p2] = ((unsigned int)(r.z & 255) << 17) | (unsigned int)c.z;
        stage[p3] = ((unsigned int)(r.w & 255) << 17) | (unsigned int)c.w;
    }
    __syncthreads();

    // pass 4: coalesced full-line flush (write amp 1.0)
    unsigned int* dst = binned + (size_t)b * BINSTRIDE;
    for (int i = tid; i < CHUNK; i += BTHR) dst[i] = stage[i];
}

// ---------------------------------------------------------------------------
// B. Bucket accumulate (R17-verified, byte-identical). 500 sub-runs x 2
//    lanes; pass-1 register-caches edges (ev[12]); single-wave shuffle
//    scan; bijective XCD-chunked bucket swizzle; atomic-free pass-4 with
//    2 lanes/node x 16B gathers from L2-resident xcon.
// ---------------------------------------------------------------------------
__global__ __launch_bounds__(1024, 2) void agg_kernel(
    const __half* __restrict__ xcon, const int* __restrict__ cnts,
    const int* __restrict__ offs,
    const unsigned int* __restrict__ binned, __half* __restrict__ agg) {
    __shared__ unsigned int sedge[CAP];   // 40 KB
    __shared__ int scnt[NPB];
    __shared__ int soff[NPB];
    int orig = blockIdx.x;
    int xcd = orig & 7, i8 = orig >> 3;
    const int qq = NBKT >> 3, rr = NBKT & 7;
    int b = (xcd < rr) ? xcd * (qq + 1) + i8
                       : rr * (qq + 1) + (xcd - rr) * qq + i8;
    int tid = threadIdx.x;
    if (tid < NPB) scnt[tid] = 0;
    __syncthreads();

    int sub = tid >> 1, l = tid & 1;      // 500 sub-runs, 2 lanes each
    int sc = 0; unsigned int base = 0;
    if (sub < NBLK_A) {
        sc   = cnts[b * NBLK_A + sub];
        base = (unsigned int)sub * BINSTRIDE
             + (unsigned int)offs[b * NBLK_A + sub];
    }

    // pass 1: load+cache sub-run edges, per-node counts
    unsigned int ev[12];
    #pragma unroll
    for (int u = 0; u < 12; u++) {
        int j = l + 2 * u;
        ev[u] = 0u;
        if (j < sc) {
            ev[u] = binned[base + j];
            atomicAdd(&scnt[ev[u] >> 17], 1);
        }
    }
    for (int j = l + 24; j < sc; j += 2)
        atomicAdd(&scnt[binned[base + j] >> 17], 1);
    __syncthreads();

    // pass 2: exclusive scan of 256 counts by wave 0 (shuffle scan)
    if (tid < 64) {
        int i0 = tid * 4;
        int c0 = scnt[i0], c1 = scnt[i0 + 1], c2 = scnt[i0 + 2], c3 = scnt[i0 + 3];
        int s = c0 + c1 + c2 + c3;
        int t = s;
        #pragma unroll
        for (int off = 1; off < 64; off <<= 1) {
            int u = __shfl_up(t, off, 64);
            if (tid >= off) t += u;
        }
        int ex = t - s;
        soff[i0]     = ex;
        soff[i0 + 1] = ex + c0;
        soff[i0 + 2] = ex + c0 + c1;
        soff[i0 + 3] = ex + c0 + c1 + c2;
    }
    __syncthreads();

    // pass 3: scatter into node-sorted sedge from the register cache
    #pragma unroll
    for (int u = 0; u < 12; u++) {
        int j = l + 2 * u;
        if (j < sc) {
            unsigned int p = ev[u];
            int pos = atomicAdd(&soff[p >> 17], 1);
            sedge[pos] = p & 0x1FFFFu;
        }
    }
    for (int j = l + 24; j < sc; j += 2) {
        unsigned int p = binned[base + j];
        int pos = atomicAdd(&soff[p >> 17], 1);
        sedge[pos] = p & 0x1FFFFu;
    }
    __syncthreads();

    // pass 4: accumulate, 2 lanes/node, 16B gathers from L2-resident xcon
    if (tid < 2 * NPB) {
        int nl = tid >> 1, q = tid & 1;
        int c  = scnt[nl];
        int s0 = soff[nl] - c;                 // soff advanced to row end
        float a0 = 0.f, a1 = 0.f, a2 = 0.f, a3 = 0.f;
        float a4 = 0.f, a5 = 0.f, a6 = 0.f, a7 = 0.f;
        #pragma unroll 2
        for (int k = 0; k < c; k++) {
            int col = (int)sedge[s0 + k];      // broadcast within pair
            uint4 raw = ((const uint4*)(xcon + (size_t)col * 16))[q];
            float2 f0 = __half22float2(*(const __half2*)&raw.x);
            float2 f1 = __half22float2(*(const __half2*)&raw.y);
            float2 f2 = __half22float2(*(const __half2*)&raw.z);
            float2 f3 = __half22float2(*(const __half2*)&raw.w);
            a0 += f0.x; a1 += f0.y; a2 += f1.x; a3 += f1.y;
            a4 += f2.x; a5 += f2.y; a6 += f3.x; a7 += f3.y;
        }
        int n = b * NPB + nl;
        if (n < N_NODES) {
            float inv = 1.0f / (float)max(c, 1);
            __half2 h0 = __floats2half2_rn(a0 * inv, a1 * inv);
            __half2 h1 = __floats2half2_rn(a2 * inv, a3 * inv);
            __half2 h2 = __floats2half2_rn(a4 * inv, a5 * inv);
            __half2 h3 = __floats2half2_rn(a6 * inv, a7 * inv);
            uint4 st;
            st.x = *(unsigned int*)&h0; st.y = *(unsigned int*)&h1;
            st.z = *(unsigned int*)&h2; st.w = *(unsigned int*)&h3;
            *(uint4*)(agg + (size_t)n * 16 + q * 8) = st;   // 16B/lane
        }
    }
}

// ---------------------------------------------------------------------------
// C. MLP, R18: v_dot2_f32_f16 path. Phase A: radial stays f32 FMA (16/h),
//    conical uses fdot2 on agg's native half2 (EXACT repack, 8/h) — 384 vs
//    512 VALU per wave. Phase B: H2 pairs consumed directly as half2 via
//    fdot2 against f16 W2^T — 256 vs 512 VALU. f32 accumulation throughout.
//    Structure (8 waves / 64-node tile, wave-uniform weight rows on the
//    scalar pipe) is the R9..R17-verified one.
// ---------------------------------------------------------------------------
__global__ __launch_bounds__(512, 4) void mlp_kernel(
    const float* __restrict__ x, const __half* __restrict__ agg,
    const float* __restrict__ W1tr, const __half* __restrict__ W1th,
    const float* __restrict__ b1,
    const __half* __restrict__ W2th, const float* __restrict__ b2,
    float* __restrict__ out, int N) {
    __shared__ __half2 H2[64 * 64];   // [kp][node], 16 KB
    int tid  = threadIdx.x;
    int lane = tid & 63;
    int ws   = __builtin_amdgcn_readfirstlane(tid >> 6);
    int n    = blockIdx.x * 64 + lane;
    int nc   = min(n, N - 1);

    float combr[16];
    const float4* xr = (const float4*)(x + (size_t)nc * 32);
    #pragma unroll
    for (int c = 0; c < 4; c++) {
        float4 v = xr[c];
        combr[c*4+0] = v.x; combr[c*4+1] = v.y;
        combr[c*4+2] = v.z; combr[c*4+3] = v.w;
    }
    __half2 aggh[8];
    const __half2* ar = (const __half2*)(agg + (size_t)nc * 16);
    #pragma unroll
    for (int c = 0; c < 8; c++) aggh[c] = ar[c];

    #pragma unroll
    for (int i = 0; i < 16; i += 2) {
        int k0 = ws * 16 + i;
        const float*   w1a  = W1tr + k0 * 16;
        const float*   w1b  = w1a + 16;
        const __half2* w1ha = (const __half2*)(W1th + k0 * 16);
        const __half2* w1hb = w1ha + 8;
        float ha = b1[k0], hb = b1[k0 + 1];
        #pragma unroll
        for (int c = 0; c < 16; c++) {
            ha = fmaf(combr[c], w1a[c], ha);
            hb = fmaf(combr[c], w1b[c], hb);
        }
        #pragma unroll
        for (int p = 0; p < 8; p++) {
            ha = fdot2(aggh[p], w1ha[p], ha);
            hb = fdot2(aggh[p], w1hb[p], hb);
        }
        ha = fmaxf(ha, 0.f); hb = fmaxf(hb, 0.f);
        H2[(k0 >> 1) * 64 + lane] = __floats2half2_rn(ha, hb);
    }
    __syncthreads();

    int o0 = ws * 4;
    const __half2* w20 = (const __half2*)(W2th + (o0 + 0) * 128);
    const __half2* w21 = (const __half2*)(W2th + (o0 + 1) * 128);
    const __half2* w22 = (const __half2*)(W2th + (o0 + 2) * 128);
    const __half2* w23 = (const __half2*)(W2th + (o0 + 3) * 128);
    float acc0 = b2[o0+0], acc1 = b2[o0+1], acc2 = b2[o0+2], acc3 = b2[o0+3];
    #pragma unroll 8
    for (int kp = 0; kp < 64; kp++) {
        __half2 hq = H2[kp * 64 + lane];
        acc0 = fdot2(hq, w20[kp], acc0);
        acc1 = fdot2(hq, w21[kp], acc1);
        acc2 = fdot2(hq, w22[kp], acc2);
        acc3 = fdot2(hq, w23[kp], acc3);
    }
    if (n < N) {
        float* op = out + (size_t)n * 32 + o0;
        op[0] = acc0; op[1] = acc1; op[2] = acc2; op[3] = acc3;
    }
}

extern "C" void kernel_launch(void* const* d_in, const int* in_sizes, int n_in,
                              void* d_out, int out_size, void* d_ws, size_t ws_size,
                              hipStream_t stream) {
    const float* x   = (const float*)d_in[0];
    const int*   idx = (const int*)d_in[1];
    const float* W1  = (const float*)d_in[2];
    const float* b1  = (const float*)d_in[3];
    const float* W2  = (const float*)d_in[4];
    const float* b2  = (const float*)d_in[5];
    float* out = (float*)d_out;

    const int E = in_sizes[1] / 2;     // 1,600,000
    const int total = 2 * E;           // 3,200,000

    // ws layout (~21 MB):
    //   agg 3.2MB | xcon 3.2MB | W1tr 8KB | W1th 4KB | W2th 8KB |
    //   cnts 782KB | offs 782KB | binned 500*6400*4 = 12.8MB
    char* base = (char*)d_ws;
    __half*       agg    = (__half*)base;
    __half*       xcon   = (__half*)(base + 3203072);
    float*        W1tr   = (float*)(base + 6406144);
    __half*       W1th   = (__half*)(base + 6414336);
    __half*       W2th   = (__half*)(base + 6418432);
    int*          cnts   = (int*)(base + 6426624);
    int*          offs   = (int*)(base + 7208960);
    unsigned int* binned = (unsigned int*)(base + 7991296);

    int pack_blocks = (N_NODES * 4 + BTHR - 1) / BTHR;   // 782
    binfuse_kernel<<<NBLK_A + 1 + pack_blocks, BTHR, 0, stream>>>(
        idx, x, (__half2*)xcon, W1, W2, W1tr, W1th, W2th,
        binned, cnts, offs, total, E);
    agg_kernel<<<NBKT, 1024, 0, stream>>>(xcon, cnts, offs, binned, agg);
    mlp_kernel<<<(N_NODES + 63) / 64, 512, 0, stream>>>(
        x, agg, W1tr, W1th, b1, W2th, b2, out, N_NODES);
}